// Round 17
// baseline (80.118 us; speedup 1.0000x reference)
//
#include <hip/hip_runtime.h>
#include <hip/hip_bf16.h>

#define DIM   1024
#define SEQL  4096
#define NTOK  16384
#define NATT  90
#define NATTP 96

typedef __attribute__((ext_vector_type(8))) short frag_ab;   // 8 x bf16
typedef __attribute__((ext_vector_type(4))) float frag_cd;   // 4 x f32

typedef unsigned int u32;
typedef const __attribute__((address_space(1))) u32* gp_t;
typedef __attribute__((address_space(3))) u32* lp_t;

static __device__ __forceinline__ unsigned short f2bf(float f) {
    unsigned int u = __float_as_uint(f);
    return (unsigned short)((u + 0x7fffu + ((u >> 16) & 1u)) >> 16);  // RNE
}
static __device__ __forceinline__ ushort4 f4tobf(float4 v) {
    ushort4 r; r.x = f2bf(v.x); r.y = f2bf(v.y); r.z = f2bf(v.z); r.w = f2bf(v.w);
    return r;
}
static __device__ __forceinline__ float4 bf4tof(ushort4 u) {
    float4 r;
    r.x = __uint_as_float((u32)u.x << 16);
    r.y = __uint_as_float((u32)u.y << 16);
    r.z = __uint_as_float((u32)u.z << 16);
    r.w = __uint_as_float((u32)u.w << 16);
    return r;
}

// ---------- w2 -> fragment-packed bf16 (48 blocks; must precede att_y) ----------
__global__ __launch_bounds__(256) void cvt_w2_kernel(
    const float* __restrict__ w2, unsigned short* __restrict__ w2p)
{
    const int idx = blockIdx.x * 256 + threadIdx.x;   // 0..12287
    const int c    = idx / 384;
    const int rem  = idx - c * 384;
    const int f    = rem >> 6;
    const int lane = rem & 63;
    const int row  = f * 16 + (lane & 15);
    const int col  = c * 32 + (lane >> 4) * 8;
    float4 v0 = make_float4(0.f, 0.f, 0.f, 0.f), v1 = v0;
    if (row < NATT) {
        v0 = *(const float4*)(w2 + (size_t)row * DIM + col);
        v1 = *(const float4*)(w2 + (size_t)row * DIM + col + 4);
    }
    unsigned short* dst = w2p + (size_t)idx * 8;
    *(ushort4*)(dst)     = f4tobf(v0);
    *(ushort4*)(dst + 4) = f4tobf(v1);
}

// ---------- fused: att -> coeff -> y stencil -> ybf  (+ wo cvt on blocks >= 1024) ----
#define ATOK 16
#define PSTR 98

__global__ __launch_bounds__(256) void att_y_kernel(
    const float* __restrict__ x, const unsigned short* __restrict__ w2p,
    const float* __restrict__ b2, const float* __restrict__ wo,
    unsigned short* __restrict__ ybf, unsigned short* __restrict__ wob)
{
    __shared__ __align__(16) unsigned short xs[ATOK * 1024];  // 32 KB, chunk-swizzled
    __shared__ float part[ATOK * PSTR];                       // 6.1 KB (single copy)
    __shared__ float b2s[NATTP];
    __shared__ float coe[ATOK][12];

    const int tid  = threadIdx.x;
    const int bid = blockIdx.x;

    if (bid >= 1024) {
        // wo -> bf16 (consumed only by gemm, launched after us). One float4/thread.
        const int i = (bid - 1024) * 256 + tid;
        float4 v = ((const float4*)wo)[i];
        *(ushort4*)(wob + (size_t)i * 4) = f4tobf(v);
        return;
    }

    const int wave = tid >> 6, lane = tid & 63;
    const int fr = lane & 15, kq = lane >> 4;
    const int lid = (bid & 7) * 128 + (bid >> 3);   // bijective XCD swizzle
    const int tok0 = lid * ATOK;
    const int bb = tok0 >> 12;
    const int l0 = tok0 & 4095;

    if (tid < NATTP) b2s[tid] = (tid < NATT) ? b2[tid] : 0.f;

    // stage x: each wave loads 4 full rows coalesced, swizzled bf16 store.
    #pragma unroll
    for (int t = 0; t < 4; ++t) {
        const int row = t * 4 + wave;
        const float4* xr = (const float4*)(x + (size_t)(tok0 + row) * DIM);
        #pragma unroll
        for (int tt = 0; tt < 4; ++tt) {
            const int c4 = tt * 64 + lane;
            float4 v = xr[c4];
            const int ch = c4 >> 1, half = c4 & 1;
            *(ushort4*)(&xs[row * 1024 + ((ch ^ (row & 7)) * 8 + half * 4)]) = f4tobf(v);
        }
    }

    // halo loads issued early; mostly XCD-L2 hits after swizzle.
    const float4 z4 = make_float4(0.f, 0.f, 0.f, 0.f);
    float4 halo[8];
    #pragma unroll
    for (int hh = 0; hh < 8; ++hh) {
        const int off = (hh < 4) ? (hh - 4) : (hh + 12);
        const int src = l0 + off;
        halo[hh] = z4;
        if (src >= 0 && src < SEQL)
            halo[hh] = *((const float4*)(x + ((size_t)bb * SEQL + src) * DIM) + tid);
    }
    __syncthreads();

    // MFMA: wave w owns K-half (w>>1) x f-frags {3(w&1) .. 3(w&1)+2}
    const int fbase = (wave & 1) * 3;
    const int kh    = wave >> 1;
    frag_cd acc[3] = {};
    #pragma unroll
    for (int kk = 0; kk < 16; ++kk) {
        const int ch = kh * 64 + kk * 4 + kq;         // 16B-chunk idx
        frag_ab a = *(const frag_ab*)(&xs[fr * 1024 + ((ch ^ (fr & 7)) * 8)]);
        const int c = kh * 16 + kk;                   // 32-col chunk idx 0..31
        #pragma unroll
        for (int ff = 0; ff < 3; ++ff) {
            const int f = fbase + ff;
            frag_ab b = *(const frag_ab*)(w2p + ((size_t)((c * 6 + f) * 64) + lane) * 8);
            acc[ff] = __builtin_amdgcn_mfma_f32_16x16x32_bf16(a, b, acc[ff], 0, 0, 0);
        }
    }

    // 2-step parallel reduction: waves 0,1 (kh=0) write disjoint cols (+bias);
    // waves 2,3 (kh=1) add to disjoint cols.
    const int col = lane & 15, rb = (lane >> 4) * 4;
    if (kh == 0) {
        #pragma unroll
        for (int ff = 0; ff < 3; ++ff)
            #pragma unroll
            for (int r = 0; r < 4; ++r)
                part[(rb + r) * PSTR + (fbase + ff) * 16 + col]
                    = acc[ff][r] + b2s[(fbase + ff) * 16 + col];
    }
    __syncthreads();
    if (kh == 1) {
        #pragma unroll
        for (int ff = 0; ff < 3; ++ff)
            #pragma unroll
            for (int r = 0; r < 4; ++r)
                part[(rb + r) * PSTR + (fbase + ff) * 16 + col] += acc[ff][r];
    }
    __syncthreads();

    // coeff[k] = sum_j sin(att[9k+j]);  absum = sum att[81..89]
    if (tid < 160) {
        const int t = tid / 10, j = tid - (tid / 10) * 10;
        float s = 0.f;
        if (j < 9) {
            #pragma unroll
            for (int jj = 0; jj < 9; ++jj) s += sinf(part[t * PSTR + j * 9 + jj]);
        } else {
            #pragma unroll
            for (int m = NATT - 9; m < NATT; ++m) s += part[t * PSTR + m];
        }
        coe[t][j] = s;
    }
    __syncthreads();

    // y phase: rolling window; interior rows from LDS xs, halo from regs
    const int ch2 = tid >> 1, hf2 = tid & 1;
    auto rowval = [&](int rel) -> float4 {
        if (rel < 0)  return halo[rel + 4];
        if (rel > 15) return halo[rel - 12];
        ushort4 u = *(const ushort4*)(&xs[rel * 1024 + ((ch2 ^ (rel & 7)) * 8 + hf2 * 4)]);
        return bf4tof(u);
    };

    float4 w[9];
    #pragma unroll
    for (int k = 0; k < 8; ++k) w[k] = rowval(k - 4);

    #pragma unroll
    for (int t = 0; t < ATOK; ++t) {
        w[8] = rowval(t + 4);
        float4 a4;
        a4.x = a4.y = a4.z = a4.w = coe[t][9];
        #pragma unroll
        for (int k = 0; k < 9; ++k) {
            const float ck = coe[t][k];
            a4.x += ck * w[k].x; a4.y += ck * w[k].y;
            a4.z += ck * w[k].z; a4.w += ck * w[k].w;
        }
        *(ushort4*)(ybf + (size_t)(tok0 + t) * DIM + tid * 4) = f4tobf(a4);
        #pragma unroll
        for (int k = 0; k < 8; ++k) w[k] = w[k + 1];
    }
}

// ---------- stage 3: out = y @ wo^T + bo ----------
// R5 counted-vmcnt skeleton at 128x128 tile, BK=64, 4 waves (wave tile 64x64).
// Per-thread staging identical to R5 (8 gload_lds/tile -> same vmcnt(8)).
// LDS 64 KB -> 2 blocks/CU: cross-block overlap hides barrier drains (m114).
// Guide tile-sweep at this structure class: 128^2=912 TF vs 256^2=792 TF.
#define GBM 128
#define GBN 128
#define GBK 64

#define STAGE(d, kt)                                                           \
    {                                                                          \
        const int kc_ = (kt) * GBK;                                            \
        _Pragma("unroll")                                                      \
        for (int j_ = 0; j_ < 4; ++j_) {                                       \
            __builtin_amdgcn_global_load_lds(                                  \
                (gp_t)(A + (size_t)(m0 + srow[j_]) * DIM + kc_ + scol[j_]),    \
                (lp_t)(&As[d][(wave * 4 + j_) * 512]), 16, 0, 0);              \
            __builtin_amdgcn_global_load_lds(                                  \
                (gp_t)(Bm + (size_t)(n0 + srow[j_]) * DIM + kc_ + scol[j_]),   \
                (lp_t)(&Bs[d][(wave * 4 + j_) * 512]), 16, 0, 0);              \
        }                                                                      \
    }

__global__ __launch_bounds__(256, 2) void gemm_kernel(
    const unsigned short* __restrict__ A,   // y_bf  [16384][1024]
    const unsigned short* __restrict__ Bm,  // wo_bf [1024][1024] (row = out col)
    const float* __restrict__ bo,
    float* __restrict__ out)
{
    __shared__ unsigned short As[2][GBM * GBK];   // 2 x 16 KB
    __shared__ unsigned short Bs[2][GBN * GBK];   // 2 x 16 KB

    const int tid  = threadIdx.x;
    const int wave = tid >> 6, lane = tid & 63;
    const int fr = lane & 15, kq = lane >> 4;
    const int wm = (wave >> 1) * 64;     // 0 or 64
    const int wn = (wave & 1) * 64;      // 0 or 64

    // bijective XCD swizzle: 1024 blocks = 8 XCDs x 128; XCD owns 16 contiguous M-panels
    const int bid = blockIdx.x;
    const int lid = (bid & 7) * 128 + (bid >> 3);
    const int m0  = (lid >> 3) * GBM;
    const int n0  = (lid & 7) * GBN;

    int srow[4], scol[4];
    #pragma unroll
    for (int j = 0; j < 4; ++j) {
        int ci = (wave * 4 + j) * 64 + lane;     // 0..1023 chunk idx
        int row = ci >> 3;                       // 0..127
        srow[j] = row;
        scol[j] = ((ci & 7) ^ (row & 7)) * 8;    // pre-swizzled global source
    }

    frag_cd acc[4][4] = {};

    STAGE(0, 0);
    STAGE(1, 1);

    for (int kt = 0; kt < 15; ++kt) {
        const int d = kt & 1;
        asm volatile("s_waitcnt vmcnt(8)" ::: "memory");   // kt landed; kt+1 in flight
        __builtin_amdgcn_s_barrier();

        frag_ab b0[4], b1[4];
        #pragma unroll
        for (int ni = 0; ni < 4; ++ni) {
            int row = wn + ni * 16 + fr;
            b0[ni] = *(const frag_ab*)(&Bs[d][row * 64 + ((kq       ^ (row & 7)) * 8)]);
            b1[ni] = *(const frag_ab*)(&Bs[d][row * 64 + (((4 + kq) ^ (row & 7)) * 8)]);
        }
        frag_ab alo0[2], alo1[2];
        #pragma unroll
        for (int mi = 0; mi < 2; ++mi) {
            int row = wm + mi * 16 + fr;
            alo0[mi] = *(const frag_ab*)(&As[d][row * 64 + ((kq       ^ (row & 7)) * 8)]);
            alo1[mi] = *(const frag_ab*)(&As[d][row * 64 + (((4 + kq) ^ (row & 7)) * 8)]);
        }
        __builtin_amdgcn_s_setprio(1);
        #pragma unroll
        for (int mi = 0; mi < 2; ++mi)
            #pragma unroll
            for (int ni = 0; ni < 4; ++ni) {
                acc[mi][ni] = __builtin_amdgcn_mfma_f32_16x16x32_bf16(alo0[mi], b0[ni], acc[mi][ni], 0, 0, 0);
                acc[mi][ni] = __builtin_amdgcn_mfma_f32_16x16x32_bf16(alo1[mi], b1[ni], acc[mi][ni], 0, 0, 0);
            }
        __builtin_amdgcn_s_setprio(0);
        frag_ab ahi0[2], ahi1[2];
        #pragma unroll
        for (int mi = 0; mi < 2; ++mi) {
            int row = wm + (mi + 2) * 16 + fr;
            ahi0[mi] = *(const frag_ab*)(&As[d][row * 64 + ((kq       ^ (row & 7)) * 8)]);
            ahi1[mi] = *(const frag_ab*)(&As[d][row * 64 + (((4 + kq) ^ (row & 7)) * 8)]);
        }
        asm volatile("s_waitcnt lgkmcnt(0)" ::: "memory");
        __builtin_amdgcn_s_barrier();
        if (kt < 14) { STAGE(d, kt + 2); }
        __builtin_amdgcn_s_setprio(1);
        #pragma unroll
        for (int mi = 0; mi < 2; ++mi)
            #pragma unroll
            for (int ni = 0; ni < 4; ++ni) {
                acc[mi + 2][ni] = __builtin_amdgcn_mfma_f32_16x16x32_bf16(ahi0[mi], b0[ni], acc[mi + 2][ni], 0, 0, 0);
                acc[mi + 2][ni] = __builtin_amdgcn_mfma_f32_16x16x32_bf16(ahi1[mi], b1[ni], acc[mi + 2][ni], 0, 0, 0);
            }
        __builtin_amdgcn_s_setprio(0);
    }

    {
        asm volatile("s_waitcnt vmcnt(0)" ::: "memory");
        __builtin_amdgcn_s_barrier();
        frag_ab b0[4], b1[4];
        #pragma unroll
        for (int ni = 0; ni < 4; ++ni) {
            int row = wn + ni * 16 + fr;
            b0[ni] = *(const frag_ab*)(&Bs[1][row * 64 + ((kq       ^ (row & 7)) * 8)]);
            b1[ni] = *(const frag_ab*)(&Bs[1][row * 64 + (((4 + kq) ^ (row & 7)) * 8)]);
        }
        #pragma unroll
        for (int h = 0; h < 2; ++h) {
            frag_ab a0[2], a1[2];
            #pragma unroll
            for (int mi = 0; mi < 2; ++mi) {
                int row = wm + (mi + h * 2) * 16 + fr;
                a0[mi] = *(const frag_ab*)(&As[1][row * 64 + ((kq       ^ (row & 7)) * 8)]);
                a1[mi] = *(const frag_ab*)(&As[1][row * 64 + (((4 + kq) ^ (row & 7)) * 8)]);
            }
            __builtin_amdgcn_s_setprio(1);
            #pragma unroll
            for (int mi = 0; mi < 2; ++mi)
                #pragma unroll
                for (int ni = 0; ni < 4; ++ni) {
                    acc[mi + h * 2][ni] = __builtin_amdgcn_mfma_f32_16x16x32_bf16(a0[mi], b0[ni], acc[mi + h * 2][ni], 0, 0, 0);
                    acc[mi + h * 2][ni] = __builtin_amdgcn_mfma_f32_16x16x32_bf16(a1[mi], b1[ni], acc[mi + h * 2][ni], 0, 0, 0);
                }
            __builtin_amdgcn_s_setprio(0);
        }
    }

    // epilogue
    const int colb = lane & 15, rb = (lane >> 4) * 4;
    #pragma unroll
    for (int ni = 0; ni < 4; ++ni) {
        const int col = n0 + wn + ni * 16 + colb;
        const float bias = bo[col];
        #pragma unroll
        for (int mi = 0; mi < 4; ++mi) {
            #pragma unroll
            for (int r = 0; r < 4; ++r) {
                const int row = m0 + wm + mi * 16 + rb + r;
                out[(size_t)row * DIM + col] = acc[mi][ni][r] + bias;
            }
        }
    }
}

// ---------- launch ----------
extern "C" void kernel_launch(void* const* d_in, const int* in_sizes, int n_in,
                              void* d_out, int out_size, void* d_ws, size_t ws_size,
                              hipStream_t stream) {
    const float* x  = (const float*)d_in[0];
    const float* w2 = (const float*)d_in[1];
    const float* b2 = (const float*)d_in[2];
    const float* wo = (const float*)d_in[3];
    const float* bo = (const float*)d_in[4];
    float* out = (float*)d_out;

    char* ws = (char*)d_ws;
    unsigned short* wob = (unsigned short*)ws;                       // 2 MB
    unsigned short* ybf = (unsigned short*)(ws + 2097152);           // 32 MB
    unsigned short* w2p = (unsigned short*)(ws + 2097152 + 33554432);// 192 KB

    cvt_w2_kernel<<<48, 256, 0, stream>>>(w2, w2p);
    att_y_kernel<<<2048, 256, 0, stream>>>(x, w2p, b2, wo, ybf, wob);
    gemm_kernel<<<NTOK / GBM * (DIM / GBN), 256, 0, stream>>>(ybf, wob, bo, out);
}

// Round 18
// 79.565 us; speedup vs baseline: 1.0069x; 1.0069x over previous
//
#include <hip/hip_runtime.h>
#include <hip/hip_bf16.h>

#define DIM   1024
#define SEQL  4096
#define NTOK  16384
#define NATT  90
#define NATTP 96

typedef __attribute__((ext_vector_type(8))) short frag_ab;   // 8 x bf16
typedef __attribute__((ext_vector_type(4))) float frag_cd;   // 4 x f32

typedef unsigned int u32;
typedef const __attribute__((address_space(1))) u32* gp_t;
typedef __attribute__((address_space(3))) u32* lp_t;

static __device__ __forceinline__ unsigned short f2bf(float f) {
    unsigned int u = __float_as_uint(f);
    return (unsigned short)((u + 0x7fffu + ((u >> 16) & 1u)) >> 16);  // RNE
}
static __device__ __forceinline__ ushort4 f4tobf(float4 v) {
    ushort4 r; r.x = f2bf(v.x); r.y = f2bf(v.y); r.z = f2bf(v.z); r.w = f2bf(v.w);
    return r;
}
static __device__ __forceinline__ float4 bf4tof(ushort4 u) {
    float4 r;
    r.x = __uint_as_float((u32)u.x << 16);
    r.y = __uint_as_float((u32)u.y << 16);
    r.z = __uint_as_float((u32)u.z << 16);
    r.w = __uint_as_float((u32)u.w << 16);
    return r;
}

// ---------- w2 -> fragment-packed bf16 (48 blocks; must precede att_y) ----------
__global__ __launch_bounds__(256) void cvt_w2_kernel(
    const float* __restrict__ w2, unsigned short* __restrict__ w2p)
{
    const int idx = blockIdx.x * 256 + threadIdx.x;   // 0..12287
    const int c    = idx / 384;
    const int rem  = idx - c * 384;
    const int f    = rem >> 6;
    const int lane = rem & 63;
    const int row  = f * 16 + (lane & 15);
    const int col  = c * 32 + (lane >> 4) * 8;
    float4 v0 = make_float4(0.f, 0.f, 0.f, 0.f), v1 = v0;
    if (row < NATT) {
        v0 = *(const float4*)(w2 + (size_t)row * DIM + col);
        v1 = *(const float4*)(w2 + (size_t)row * DIM + col + 4);
    }
    unsigned short* dst = w2p + (size_t)idx * 8;
    *(ushort4*)(dst)     = f4tobf(v0);
    *(ushort4*)(dst + 4) = f4tobf(v1);
}

// ---------- fused: att -> coeff -> y stencil -> ybf  (+ wo cvt on blocks >= 512) ----
// 512 threads, 32 tokens/block: doubles resident waves/CU under the observed
// ~2-blocks/CU cap; halves per-token halo and w2p traffic. LDS 80 KB -> 2/CU.
#define ATOK 32
#define PSTR 98

__global__ __launch_bounds__(512, 4) void att_y_kernel(
    const float* __restrict__ x, const unsigned short* __restrict__ w2p,
    const float* __restrict__ b2, const float* __restrict__ wo,
    unsigned short* __restrict__ ybf, unsigned short* __restrict__ wob)
{
    __shared__ __align__(16) unsigned short xs[ATOK * 1024];  // 64 KB, chunk-swizzled
    __shared__ float part[ATOK * PSTR];                       // 12.25 KB
    __shared__ float b2s[NATTP];
    __shared__ float coe[ATOK][12];

    const int tid = threadIdx.x;
    const int bid = blockIdx.x;

    if (bid >= 512) {
        // wo -> bf16 (consumed only by gemm). One float4/thread:
        // 512 blocks x 512 thr = 262144 = 1024*1024/4.
        const int i = (bid - 512) * 512 + tid;
        float4 v = ((const float4*)wo)[i];
        *(ushort4*)(wob + (size_t)i * 4) = f4tobf(v);
        return;
    }

    const int wave = tid >> 6, lane = tid & 63;
    const int fr = lane & 15, kq = lane >> 4;
    const int lid = (bid & 7) * 64 + (bid >> 3);    // bijective XCD swizzle (512=8x64)
    const int tok0 = lid * ATOK;
    const int bb = tok0 >> 12;
    const int l0 = tok0 & 4095;

    if (tid < NATTP) b2s[tid] = (tid < NATT) ? b2[tid] : 0.f;

    // stage x: 32 rows; each of 8 waves loads 4 full rows coalesced, swizzled store.
    #pragma unroll
    for (int t = 0; t < 4; ++t) {
        const int row = t * 8 + wave;
        const float4* xr = (const float4*)(x + (size_t)(tok0 + row) * DIM);
        #pragma unroll
        for (int tt = 0; tt < 4; ++tt) {
            const int c4 = tt * 64 + lane;
            float4 v = xr[c4];
            const int ch = c4 >> 1, half = c4 & 1;
            *(ushort4*)(&xs[row * 1024 + ((ch ^ (row & 7)) * 8 + half * 4)]) = f4tobf(v);
        }
    }

    // halo: thread's token-half needs only 4 halo rows (left for th=0, right for th=1).
    const int ds = tid & 255;        // float4 dim-slice
    const int th = tid >> 8;         // token half 0/1
    const float4 z4 = make_float4(0.f, 0.f, 0.f, 0.f);
    float4 halo[4];
    #pragma unroll
    for (int j = 0; j < 4; ++j) {
        const int src = l0 + (th ? 32 + j : j - 4);
        halo[j] = z4;
        if (src >= 0 && src < SEQL)
            halo[j] = ((const float4*)(x + ((size_t)bb * SEQL + src) * DIM))[ds];
    }
    __syncthreads();

    // MFMA: wave w owns token-subtile (w>>2), K-half ((w>>1)&1), f-frags {3(w&1)..+2}
    const int ts    = wave >> 2;
    const int kh    = (wave >> 1) & 1;
    const int fbase = (wave & 1) * 3;
    frag_cd acc[3] = {};
    #pragma unroll
    for (int kk = 0; kk < 16; ++kk) {
        const int ch = kh * 64 + kk * 4 + kq;         // 16B-chunk idx
        const int arow = ts * 16 + fr;
        frag_ab a = *(const frag_ab*)(&xs[arow * 1024 + ((ch ^ (arow & 7)) * 8)]);
        const int c = kh * 16 + kk;                   // 32-col chunk idx 0..31
        #pragma unroll
        for (int ff = 0; ff < 3; ++ff) {
            const int f = fbase + ff;
            frag_ab b = *(const frag_ab*)(w2p + ((size_t)((c * 6 + f) * 64) + lane) * 8);
            acc[ff] = __builtin_amdgcn_mfma_f32_16x16x32_bf16(a, b, acc[ff], 0, 0, 0);
        }
    }

    // 2-step parallel reduction into part[32][PSTR]: kh=0 waves write (+bias),
    // kh=1 waves add; (ts, fbase) regions disjoint within each step.
    const int col = lane & 15, rb = (lane >> 4) * 4;
    float* pp = &part[ts * 16 * PSTR];
    if (kh == 0) {
        #pragma unroll
        for (int ff = 0; ff < 3; ++ff)
            #pragma unroll
            for (int r = 0; r < 4; ++r)
                pp[(rb + r) * PSTR + (fbase + ff) * 16 + col]
                    = acc[ff][r] + b2s[(fbase + ff) * 16 + col];
    }
    __syncthreads();
    if (kh == 1) {
        #pragma unroll
        for (int ff = 0; ff < 3; ++ff)
            #pragma unroll
            for (int r = 0; r < 4; ++r)
                pp[(rb + r) * PSTR + (fbase + ff) * 16 + col] += acc[ff][r];
    }
    __syncthreads();

    // coeff[k] = sum_j sin(att[9k+j]);  absum = sum att[81..89]
    if (tid < 320) {
        const int t = tid / 10, j = tid - (tid / 10) * 10;
        float s = 0.f;
        if (j < 9) {
            #pragma unroll
            for (int jj = 0; jj < 9; ++jj) s += sinf(part[t * PSTR + j * 9 + jj]);
        } else {
            #pragma unroll
            for (int m = NATT - 9; m < NATT; ++m) s += part[t * PSTR + m];
        }
        coe[t][j] = s;
    }
    __syncthreads();

    // y phase: thread handles dim-slice ds for tokens [th*16, th*16+16).
    const int ch2 = ds >> 1, hf2 = ds & 1;
    const int t0 = th * 16;
    auto rowval = [&](int rel) -> float4 {   // rel in [t0-4, t0+19]
        if (rel < 0)  return halo[rel + 4];          // only reachable for th=0
        if (rel > 31) return halo[rel - 32];         // only reachable for th=1
        ushort4 u = *(const ushort4*)(&xs[rel * 1024 + ((ch2 ^ (rel & 7)) * 8 + hf2 * 4)]);
        return bf4tof(u);
    };

    float4 w[9];
    #pragma unroll
    for (int k = 0; k < 8; ++k) w[k] = rowval(t0 + k - 4);

    #pragma unroll
    for (int t = 0; t < 16; ++t) {
        const int tok = t0 + t;
        w[8] = rowval(tok + 4);
        float4 a4;
        a4.x = a4.y = a4.z = a4.w = coe[tok][9];
        #pragma unroll
        for (int k = 0; k < 9; ++k) {
            const float ck = coe[tok][k];
            a4.x += ck * w[k].x; a4.y += ck * w[k].y;
            a4.z += ck * w[k].z; a4.w += ck * w[k].w;
        }
        *(ushort4*)(ybf + (size_t)(tok0 + tok) * DIM + ds * 4) = f4tobf(a4);
        #pragma unroll
        for (int k = 0; k < 8; ++k) w[k] = w[k + 1];
    }
}

// ---------- stage 3: out = y @ wo^T + bo ----------
// 256x256 tile, BK=64, 8 waves (2Mx4N), double-buffered LDS, counted vmcnt.
// FINAL — R5 structure, measured 42.4-43.5 us (~790 TF), conflicts 0. Six
// variants tried (R6/R8/R10 schedules, R12 32x32 shape, R17 128^2 tile) all
// regressed or tied. Do not touch.
#define GBM 256
#define GBN 256
#define GBK 64

#define STAGE(d, kt)                                                           \
    {                                                                          \
        const int kc_ = (kt) * GBK;                                            \
        _Pragma("unroll")                                                      \
        for (int j_ = 0; j_ < 4; ++j_) {                                       \
            __builtin_amdgcn_global_load_lds(                                  \
                (gp_t)(A + (size_t)(m0 + srow[j_]) * DIM + kc_ + scol[j_]),    \
                (lp_t)(&As[d][(wave * 4 + j_) * 512]), 16, 0, 0);              \
            __builtin_amdgcn_global_load_lds(                                  \
                (gp_t)(Bm + (size_t)(n0 + srow[j_]) * DIM + kc_ + scol[j_]),   \
                (lp_t)(&Bs[d][(wave * 4 + j_) * 512]), 16, 0, 0);              \
        }                                                                      \
    }

__global__ __launch_bounds__(512, 2) void gemm_kernel(
    const unsigned short* __restrict__ A,   // y_bf  [16384][1024]
    const unsigned short* __restrict__ Bm,  // wo_bf [1024][1024] (row = out col)
    const float* __restrict__ bo,
    float* __restrict__ out)
{
    __shared__ unsigned short As[2][GBM * GBK];   // 2 x 32 KB
    __shared__ unsigned short Bs[2][GBN * GBK];   // 2 x 32 KB

    const int tid  = threadIdx.x;
    const int wave = tid >> 6, lane = tid & 63;
    const int fr = lane & 15, kq = lane >> 4;
    const int wm = (wave >> 2) * 128;    // 0 or 128
    const int wn = (wave & 3) * 64;      // 0,64,128,192

    // bijective XCD swizzle: 256 blocks = 8 XCDs x 32; XCD owns 8 contiguous M-panels
    const int bid = blockIdx.x;
    const int lid = (bid & 7) * 32 + (bid >> 3);
    const int m0  = (lid >> 2) * GBM;
    const int n0  = (lid & 3) * GBN;

    int srow[4], scol[4];
    #pragma unroll
    for (int j = 0; j < 4; ++j) {
        int ci = (wave * 4 + j) * 64 + lane;
        int row = ci >> 3;
        srow[j] = row;
        scol[j] = ((ci & 7) ^ (row & 7)) * 8;    // pre-swizzled global source
    }

    frag_cd acc[8][4] = {};

    STAGE(0, 0);
    STAGE(1, 1);

    for (int kt = 0; kt < 15; ++kt) {
        const int d = kt & 1;
        asm volatile("s_waitcnt vmcnt(8)" ::: "memory");   // kt landed; kt+1 in flight
        __builtin_amdgcn_s_barrier();

        frag_ab b0[4], b1[4];
        #pragma unroll
        for (int ni = 0; ni < 4; ++ni) {
            int row = wn + ni * 16 + fr;
            b0[ni] = *(const frag_ab*)(&Bs[d][row * 64 + ((kq       ^ (row & 7)) * 8)]);
            b1[ni] = *(const frag_ab*)(&Bs[d][row * 64 + (((4 + kq) ^ (row & 7)) * 8)]);
        }
        frag_ab alo0[4], alo1[4];
        #pragma unroll
        for (int mi = 0; mi < 4; ++mi) {
            int row = wm + mi * 16 + fr;
            alo0[mi] = *(const frag_ab*)(&As[d][row * 64 + ((kq       ^ (row & 7)) * 8)]);
            alo1[mi] = *(const frag_ab*)(&As[d][row * 64 + (((4 + kq) ^ (row & 7)) * 8)]);
        }
        __builtin_amdgcn_s_setprio(1);
        #pragma unroll
        for (int mi = 0; mi < 4; ++mi)
            #pragma unroll
            for (int ni = 0; ni < 4; ++ni) {
                acc[mi][ni] = __builtin_amdgcn_mfma_f32_16x16x32_bf16(alo0[mi], b0[ni], acc[mi][ni], 0, 0, 0);
                acc[mi][ni] = __builtin_amdgcn_mfma_f32_16x16x32_bf16(alo1[mi], b1[ni], acc[mi][ni], 0, 0, 0);
            }
        __builtin_amdgcn_s_setprio(0);
        frag_ab ahi0[4], ahi1[4];
        #pragma unroll
        for (int mi = 0; mi < 4; ++mi) {
            int row = wm + (mi + 4) * 16 + fr;
            ahi0[mi] = *(const frag_ab*)(&As[d][row * 64 + ((kq       ^ (row & 7)) * 8)]);
            ahi1[mi] = *(const frag_ab*)(&As[d][row * 64 + (((4 + kq) ^ (row & 7)) * 8)]);
        }
        asm volatile("s_waitcnt lgkmcnt(0)" ::: "memory");
        __builtin_amdgcn_s_barrier();
        if (kt < 14) { STAGE(d, kt + 2); }
        __builtin_amdgcn_s_setprio(1);
        #pragma unroll
        for (int mi = 0; mi < 4; ++mi)
            #pragma unroll
            for (int ni = 0; ni < 4; ++ni) {
                acc[mi + 4][ni] = __builtin_amdgcn_mfma_f32_16x16x32_bf16(ahi0[mi], b0[ni], acc[mi + 4][ni], 0, 0, 0);
                acc[mi + 4][ni] = __builtin_amdgcn_mfma_f32_16x16x32_bf16(ahi1[mi], b1[ni], acc[mi + 4][ni], 0, 0, 0);
            }
        __builtin_amdgcn_s_setprio(0);
    }

    {
        asm volatile("s_waitcnt vmcnt(0)" ::: "memory");
        __builtin_amdgcn_s_barrier();
        frag_ab b0[4], b1[4];
        #pragma unroll
        for (int ni = 0; ni < 4; ++ni) {
            int row = wn + ni * 16 + fr;
            b0[ni] = *(const frag_ab*)(&Bs[1][row * 64 + ((kq       ^ (row & 7)) * 8)]);
            b1[ni] = *(const frag_ab*)(&Bs[1][row * 64 + (((4 + kq) ^ (row & 7)) * 8)]);
        }
        #pragma unroll
        for (int h = 0; h < 2; ++h) {
            frag_ab a0[4], a1[4];
            #pragma unroll
            for (int mi = 0; mi < 4; ++mi) {
                int row = wm + (mi + h * 4) * 16 + fr;
                a0[mi] = *(const frag_ab*)(&As[1][row * 64 + ((kq       ^ (row & 7)) * 8)]);
                a1[mi] = *(const frag_ab*)(&As[1][row * 64 + (((4 + kq) ^ (row & 7)) * 8)]);
            }
            __builtin_amdgcn_s_setprio(1);
            #pragma unroll
            for (int mi = 0; mi < 4; ++mi)
                #pragma unroll
                for (int ni = 0; ni < 4; ++ni) {
                    acc[mi + h * 4][ni] = __builtin_amdgcn_mfma_f32_16x16x32_bf16(a0[mi], b0[ni], acc[mi + h * 4][ni], 0, 0, 0);
                    acc[mi + h * 4][ni] = __builtin_amdgcn_mfma_f32_16x16x32_bf16(a1[mi], b1[ni], acc[mi + h * 4][ni], 0, 0, 0);
                }
            __builtin_amdgcn_s_setprio(0);
        }
    }

    // epilogue
    const int colb = lane & 15, rb = (lane >> 4) * 4;
    #pragma unroll
    for (int ni = 0; ni < 4; ++ni) {
        const int col = n0 + wn + ni * 16 + colb;
        const float bias = bo[col];
        #pragma unroll
        for (int mi = 0; mi < 8; ++mi) {
            #pragma unroll
            for (int r = 0; r < 4; ++r) {
                const int row = m0 + wm + mi * 16 + rb + r;
                out[(size_t)row * DIM + col] = acc[mi][ni][r] + bias;
            }
        }
    }
}

// ---------- launch ----------
extern "C" void kernel_launch(void* const* d_in, const int* in_sizes, int n_in,
                              void* d_out, int out_size, void* d_ws, size_t ws_size,
                              hipStream_t stream) {
    const float* x  = (const float*)d_in[0];
    const float* w2 = (const float*)d_in[1];
    const float* b2 = (const float*)d_in[2];
    const float* wo = (const float*)d_in[3];
    const float* bo = (const float*)d_in[4];
    float* out = (float*)d_out;

    char* ws = (char*)d_ws;
    unsigned short* wob = (unsigned short*)ws;                       // 2 MB
    unsigned short* ybf = (unsigned short*)(ws + 2097152);           // 32 MB
    unsigned short* w2p = (unsigned short*)(ws + 2097152 + 33554432);// 192 KB

    cvt_w2_kernel<<<48, 256, 0, stream>>>(w2, w2p);
    att_y_kernel<<<1024, 512, 0, stream>>>(x, w2p, b2, wo, ybf, wob);
    gemm_kernel<<<NTOK / GBM * (DIM / GBN), 512, 0, stream>>>(ybf, wob, bo, out);
}

// Round 19
// 76.428 us; speedup vs baseline: 1.0483x; 1.0410x over previous
//
#include <hip/hip_runtime.h>
#include <hip/hip_bf16.h>

#define DIM   1024
#define SEQL  4096
#define NTOK  16384
#define NATT  90
#define NATTP 96

typedef __attribute__((ext_vector_type(8))) short frag_ab;   // 8 x bf16
typedef __attribute__((ext_vector_type(4))) float frag_cd;   // 4 x f32

typedef unsigned int u32;
typedef const __attribute__((address_space(1))) u32* gp_t;
typedef __attribute__((address_space(3))) u32* lp_t;

static __device__ __forceinline__ unsigned short f2bf(float f) {
    unsigned int u = __float_as_uint(f);
    return (unsigned short)((u + 0x7fffu + ((u >> 16) & 1u)) >> 16);  // RNE
}
static __device__ __forceinline__ ushort4 f4tobf(float4 v) {
    ushort4 r; r.x = f2bf(v.x); r.y = f2bf(v.y); r.z = f2bf(v.z); r.w = f2bf(v.w);
    return r;
}
static __device__ __forceinline__ float4 bf4tof(ushort4 u) {
    float4 r;
    r.x = __uint_as_float((u32)u.x << 16);
    r.y = __uint_as_float((u32)u.y << 16);
    r.z = __uint_as_float((u32)u.z << 16);
    r.w = __uint_as_float((u32)u.w << 16);
    return r;
}

// ---------- w2 -> fragment-packed bf16 (48 blocks; must precede att_y) ----------
__global__ __launch_bounds__(256) void cvt_w2_kernel(
    const float* __restrict__ w2, unsigned short* __restrict__ w2p)
{
    const int idx = blockIdx.x * 256 + threadIdx.x;   // 0..12287
    const int c    = idx / 384;
    const int rem  = idx - c * 384;
    const int f    = rem >> 6;
    const int lane = rem & 63;
    const int row  = f * 16 + (lane & 15);
    const int col  = c * 32 + (lane >> 4) * 8;
    float4 v0 = make_float4(0.f, 0.f, 0.f, 0.f), v1 = v0;
    if (row < NATT) {
        v0 = *(const float4*)(w2 + (size_t)row * DIM + col);
        v1 = *(const float4*)(w2 + (size_t)row * DIM + col + 4);
    }
    unsigned short* dst = w2p + (size_t)idx * 8;
    *(ushort4*)(dst)     = f4tobf(v0);
    *(ushort4*)(dst + 4) = f4tobf(v1);
}

// ---------- fused: att -> coeff -> y stencil -> ybf  (+ wo cvt on blocks >= 1024) ----
// FINAL att_y: 256 thr / 16 tokens, K-half x f-half split, single-copy part.
// Occupancy lever exhausted (R14/R15/R16/R17 all ~76 us or worse).
#define ATOK 16
#define PSTR 98

__global__ __launch_bounds__(256) void att_y_kernel(
    const float* __restrict__ x, const unsigned short* __restrict__ w2p,
    const float* __restrict__ b2, const float* __restrict__ wo,
    unsigned short* __restrict__ ybf, unsigned short* __restrict__ wob)
{
    __shared__ __align__(16) unsigned short xs[ATOK * 1024];  // 32 KB, chunk-swizzled
    __shared__ float part[ATOK * PSTR];                       // 6.1 KB (single copy)
    __shared__ float b2s[NATTP];
    __shared__ float coe[ATOK][12];

    const int tid  = threadIdx.x;
    const int bid = blockIdx.x;

    if (bid >= 1024) {
        // wo -> bf16 (consumed only by gemm, launched after us). One float4/thread.
        const int i = (bid - 1024) * 256 + tid;
        float4 v = ((const float4*)wo)[i];
        *(ushort4*)(wob + (size_t)i * 4) = f4tobf(v);
        return;
    }

    const int wave = tid >> 6, lane = tid & 63;
    const int fr = lane & 15, kq = lane >> 4;
    const int lid = (bid & 7) * 128 + (bid >> 3);   // bijective XCD swizzle
    const int tok0 = lid * ATOK;
    const int bb = tok0 >> 12;
    const int l0 = tok0 & 4095;

    if (tid < NATTP) b2s[tid] = (tid < NATT) ? b2[tid] : 0.f;

    // stage x: each wave loads 4 full rows coalesced, swizzled bf16 store.
    #pragma unroll
    for (int t = 0; t < 4; ++t) {
        const int row = t * 4 + wave;
        const float4* xr = (const float4*)(x + (size_t)(tok0 + row) * DIM);
        #pragma unroll
        for (int tt = 0; tt < 4; ++tt) {
            const int c4 = tt * 64 + lane;
            float4 v = xr[c4];
            const int ch = c4 >> 1, half = c4 & 1;
            *(ushort4*)(&xs[row * 1024 + ((ch ^ (row & 7)) * 8 + half * 4)]) = f4tobf(v);
        }
    }

    // halo loads issued early; mostly XCD-L2 hits after swizzle.
    const float4 z4 = make_float4(0.f, 0.f, 0.f, 0.f);
    float4 halo[8];
    #pragma unroll
    for (int hh = 0; hh < 8; ++hh) {
        const int off = (hh < 4) ? (hh - 4) : (hh + 12);
        const int src = l0 + off;
        halo[hh] = z4;
        if (src >= 0 && src < SEQL)
            halo[hh] = *((const float4*)(x + ((size_t)bb * SEQL + src) * DIM) + tid);
    }
    __syncthreads();

    // MFMA: wave w owns K-half (w>>1) x f-frags {3(w&1) .. 3(w&1)+2}
    const int fbase = (wave & 1) * 3;
    const int kh    = wave >> 1;
    frag_cd acc[3] = {};
    #pragma unroll
    for (int kk = 0; kk < 16; ++kk) {
        const int ch = kh * 64 + kk * 4 + kq;         // 16B-chunk idx
        frag_ab a = *(const frag_ab*)(&xs[fr * 1024 + ((ch ^ (fr & 7)) * 8)]);
        const int c = kh * 16 + kk;                   // 32-col chunk idx 0..31
        #pragma unroll
        for (int ff = 0; ff < 3; ++ff) {
            const int f = fbase + ff;
            frag_ab b = *(const frag_ab*)(w2p + ((size_t)((c * 6 + f) * 64) + lane) * 8);
            acc[ff] = __builtin_amdgcn_mfma_f32_16x16x32_bf16(a, b, acc[ff], 0, 0, 0);
        }
    }

    // 2-step parallel reduction: waves 0,1 (kh=0) write disjoint cols (+bias);
    // waves 2,3 (kh=1) add to disjoint cols.
    const int col = lane & 15, rb = (lane >> 4) * 4;
    if (kh == 0) {
        #pragma unroll
        for (int ff = 0; ff < 3; ++ff)
            #pragma unroll
            for (int r = 0; r < 4; ++r)
                part[(rb + r) * PSTR + (fbase + ff) * 16 + col]
                    = acc[ff][r] + b2s[(fbase + ff) * 16 + col];
    }
    __syncthreads();
    if (kh == 1) {
        #pragma unroll
        for (int ff = 0; ff < 3; ++ff)
            #pragma unroll
            for (int r = 0; r < 4; ++r)
                part[(rb + r) * PSTR + (fbase + ff) * 16 + col] += acc[ff][r];
    }
    __syncthreads();

    // coeff[k] = sum_j sin(att[9k+j]);  absum = sum att[81..89]
    if (tid < 160) {
        const int t = tid / 10, j = tid - (tid / 10) * 10;
        float s = 0.f;
        if (j < 9) {
            #pragma unroll
            for (int jj = 0; jj < 9; ++jj) s += sinf(part[t * PSTR + j * 9 + jj]);
        } else {
            #pragma unroll
            for (int m = NATT - 9; m < NATT; ++m) s += part[t * PSTR + m];
        }
        coe[t][j] = s;
    }
    __syncthreads();

    // y phase: rolling window; interior rows from LDS xs, halo from regs
    const int ch2 = tid >> 1, hf2 = tid & 1;
    auto rowval = [&](int rel) -> float4 {
        if (rel < 0)  return halo[rel + 4];
        if (rel > 15) return halo[rel - 12];
        ushort4 u = *(const ushort4*)(&xs[rel * 1024 + ((ch2 ^ (rel & 7)) * 8 + hf2 * 4)]);
        return bf4tof(u);
    };

    float4 w[9];
    #pragma unroll
    for (int k = 0; k < 8; ++k) w[k] = rowval(k - 4);

    #pragma unroll
    for (int t = 0; t < ATOK; ++t) {
        w[8] = rowval(t + 4);
        float4 a4;
        a4.x = a4.y = a4.z = a4.w = coe[t][9];
        #pragma unroll
        for (int k = 0; k < 9; ++k) {
            const float ck = coe[t][k];
            a4.x += ck * w[k].x; a4.y += ck * w[k].y;
            a4.z += ck * w[k].z; a4.w += ck * w[k].w;
        }
        *(ushort4*)(ybf + (size_t)(tok0 + t) * DIM + tid * 4) = f4tobf(a4);
        #pragma unroll
        for (int k = 0; k < 8; ++k) w[k] = w[k + 1];
    }
}

// ---------- stage 3: out = y @ wo^T + bo ----------
// 256x256 tile, BK=64, 8 waves (2Mx4N), double-buffered LDS, counted vmcnt.
// FINAL — R5 structure, measured 42.4-43.5 us (~790 TF), conflicts 0. Six
// variants tried (R6/R8/R10 schedules, R12 32x32 shape, R17 128^2 tile) all
// regressed or tied. Do not touch.
#define GBM 256
#define GBN 256
#define GBK 64

#define STAGE(d, kt)                                                           \
    {                                                                          \
        const int kc_ = (kt) * GBK;                                            \
        _Pragma("unroll")                                                      \
        for (int j_ = 0; j_ < 4; ++j_) {                                       \
            __builtin_amdgcn_global_load_lds(                                  \
                (gp_t)(A + (size_t)(m0 + srow[j_]) * DIM + kc_ + scol[j_]),    \
                (lp_t)(&As[d][(wave * 4 + j_) * 512]), 16, 0, 0);              \
            __builtin_amdgcn_global_load_lds(                                  \
                (gp_t)(Bm + (size_t)(n0 + srow[j_]) * DIM + kc_ + scol[j_]),   \
                (lp_t)(&Bs[d][(wave * 4 + j_) * 512]), 16, 0, 0);              \
        }                                                                      \
    }

__global__ __launch_bounds__(512, 2) void gemm_kernel(
    const unsigned short* __restrict__ A,   // y_bf  [16384][1024]
    const unsigned short* __restrict__ Bm,  // wo_bf [1024][1024] (row = out col)
    const float* __restrict__ bo,
    float* __restrict__ out)
{
    __shared__ unsigned short As[2][GBM * GBK];   // 2 x 32 KB
    __shared__ unsigned short Bs[2][GBN * GBK];   // 2 x 32 KB

    const int tid  = threadIdx.x;
    const int wave = tid >> 6, lane = tid & 63;
    const int fr = lane & 15, kq = lane >> 4;
    const int wm = (wave >> 2) * 128;    // 0 or 128
    const int wn = (wave & 3) * 64;      // 0,64,128,192

    // bijective XCD swizzle: 256 blocks = 8 XCDs x 32; XCD owns 8 contiguous M-panels
    const int bid = blockIdx.x;
    const int lid = (bid & 7) * 32 + (bid >> 3);
    const int m0  = (lid >> 2) * GBM;
    const int n0  = (lid & 3) * GBN;

    int srow[4], scol[4];
    #pragma unroll
    for (int j = 0; j < 4; ++j) {
        int ci = (wave * 4 + j) * 64 + lane;
        int row = ci >> 3;
        srow[j] = row;
        scol[j] = ((ci & 7) ^ (row & 7)) * 8;    // pre-swizzled global source
    }

    frag_cd acc[8][4] = {};

    STAGE(0, 0);
    STAGE(1, 1);

    for (int kt = 0; kt < 15; ++kt) {
        const int d = kt & 1;
        asm volatile("s_waitcnt vmcnt(8)" ::: "memory");   // kt landed; kt+1 in flight
        __builtin_amdgcn_s_barrier();

        frag_ab b0[4], b1[4];
        #pragma unroll
        for (int ni = 0; ni < 4; ++ni) {
            int row = wn + ni * 16 + fr;
            b0[ni] = *(const frag_ab*)(&Bs[d][row * 64 + ((kq       ^ (row & 7)) * 8)]);
            b1[ni] = *(const frag_ab*)(&Bs[d][row * 64 + (((4 + kq) ^ (row & 7)) * 8)]);
        }
        frag_ab alo0[4], alo1[4];
        #pragma unroll
        for (int mi = 0; mi < 4; ++mi) {
            int row = wm + mi * 16 + fr;
            alo0[mi] = *(const frag_ab*)(&As[d][row * 64 + ((kq       ^ (row & 7)) * 8)]);
            alo1[mi] = *(const frag_ab*)(&As[d][row * 64 + (((4 + kq) ^ (row & 7)) * 8)]);
        }
        __builtin_amdgcn_s_setprio(1);
        #pragma unroll
        for (int mi = 0; mi < 4; ++mi)
            #pragma unroll
            for (int ni = 0; ni < 4; ++ni) {
                acc[mi][ni] = __builtin_amdgcn_mfma_f32_16x16x32_bf16(alo0[mi], b0[ni], acc[mi][ni], 0, 0, 0);
                acc[mi][ni] = __builtin_amdgcn_mfma_f32_16x16x32_bf16(alo1[mi], b1[ni], acc[mi][ni], 0, 0, 0);
            }
        __builtin_amdgcn_s_setprio(0);
        frag_ab ahi0[4], ahi1[4];
        #pragma unroll
        for (int mi = 0; mi < 4; ++mi) {
            int row = wm + (mi + 4) * 16 + fr;
            ahi0[mi] = *(const frag_ab*)(&As[d][row * 64 + ((kq       ^ (row & 7)) * 8)]);
            ahi1[mi] = *(const frag_ab*)(&As[d][row * 64 + (((4 + kq) ^ (row & 7)) * 8)]);
        }
        asm volatile("s_waitcnt lgkmcnt(0)" ::: "memory");
        __builtin_amdgcn_s_barrier();
        if (kt < 14) { STAGE(d, kt + 2); }
        __builtin_amdgcn_s_setprio(1);
        #pragma unroll
        for (int mi = 0; mi < 4; ++mi)
            #pragma unroll
            for (int ni = 0; ni < 4; ++ni) {
                acc[mi + 4][ni] = __builtin_amdgcn_mfma_f32_16x16x32_bf16(ahi0[mi], b0[ni], acc[mi + 4][ni], 0, 0, 0);
                acc[mi + 4][ni] = __builtin_amdgcn_mfma_f32_16x16x32_bf16(ahi1[mi], b1[ni], acc[mi + 4][ni], 0, 0, 0);
            }
        __builtin_amdgcn_s_setprio(0);
    }

    {
        asm volatile("s_waitcnt vmcnt(0)" ::: "memory");
        __builtin_amdgcn_s_barrier();
        frag_ab b0[4], b1[4];
        #pragma unroll
        for (int ni = 0; ni < 4; ++ni) {
            int row = wn + ni * 16 + fr;
            b0[ni] = *(const frag_ab*)(&Bs[1][row * 64 + ((kq       ^ (row & 7)) * 8)]);
            b1[ni] = *(const frag_ab*)(&Bs[1][row * 64 + (((4 + kq) ^ (row & 7)) * 8)]);
        }
        #pragma unroll
        for (int h = 0; h < 2; ++h) {
            frag_ab a0[4], a1[4];
            #pragma unroll
            for (int mi = 0; mi < 4; ++mi) {
                int row = wm + (mi + h * 4) * 16 + fr;
                a0[mi] = *(const frag_ab*)(&As[1][row * 64 + ((kq       ^ (row & 7)) * 8)]);
                a1[mi] = *(const frag_ab*)(&As[1][row * 64 + (((4 + kq) ^ (row & 7)) * 8)]);
            }
            __builtin_amdgcn_s_setprio(1);
            #pragma unroll
            for (int mi = 0; mi < 4; ++mi)
                #pragma unroll
                for (int ni = 0; ni < 4; ++ni) {
                    acc[mi + h * 4][ni] = __builtin_amdgcn_mfma_f32_16x16x32_bf16(a0[mi], b0[ni], acc[mi + h * 4][ni], 0, 0, 0);
                    acc[mi + h * 4][ni] = __builtin_amdgcn_mfma_f32_16x16x32_bf16(a1[mi], b1[ni], acc[mi + h * 4][ni], 0, 0, 0);
                }
            __builtin_amdgcn_s_setprio(0);
        }
    }

    // epilogue
    const int colb = lane & 15, rb = (lane >> 4) * 4;
    #pragma unroll
    for (int ni = 0; ni < 4; ++ni) {
        const int col = n0 + wn + ni * 16 + colb;
        const float bias = bo[col];
        #pragma unroll
        for (int mi = 0; mi < 8; ++mi) {
            #pragma unroll
            for (int r = 0; r < 4; ++r) {
                const int row = m0 + wm + mi * 16 + rb + r;
                out[(size_t)row * DIM + col] = acc[mi][ni][r] + bias;
            }
        }
    }
}

// ---------- launch ----------
extern "C" void kernel_launch(void* const* d_in, const int* in_sizes, int n_in,
                              void* d_out, int out_size, void* d_ws, size_t ws_size,
                              hipStream_t stream) {
    const float* x  = (const float*)d_in[0];
    const float* w2 = (const float*)d_in[1];
    const float* b2 = (const float*)d_in[2];
    const float* wo = (const float*)d_in[3];
    const float* bo = (const float*)d_in[4];
    float* out = (float*)d_out;

    char* ws = (char*)d_ws;
    unsigned short* wob = (unsigned short*)ws;                       // 2 MB
    unsigned short* ybf = (unsigned short*)(ws + 2097152);           // 32 MB
    unsigned short* w2p = (unsigned short*)(ws + 2097152 + 33554432);// 192 KB

    cvt_w2_kernel<<<48, 256, 0, stream>>>(w2, w2p);
    att_y_kernel<<<2048, 256, 0, stream>>>(x, w2p, b2, wo, ybf, wob);
    gemm_kernel<<<NTOK / GBM * (DIM / GBN), 512, 0, stream>>>(ybf, wob, bo, out);
}